// Round 12
// baseline (131.381 us; speedup 1.0000x reference)
//
#include <hip/hip_runtime.h>

#define T_LEN 16384
#define CIN   64
#define COUT  64
#define KTAPS 127
#define TN    512          // t-tile per block
#define XROWS 640          // staged x rows
#define XPITCH_B 144       // row pitch in bytes (128 data + 16 pad)
#define WT_KS 4096         // COUT*CIN halfwords per tap slice

typedef __attribute__((ext_vector_type(8)))  __bf16 bf16x8;
typedef __attribute__((ext_vector_type(16))) float  f32x16;
typedef __attribute__((ext_vector_type(4)))  float  float4v;

__device__ inline unsigned short f2bf(float f) {
    unsigned u = __builtin_bit_cast(unsigned, f);
    u += 0x7fffu + ((u >> 16) & 1u);        // round-to-nearest-even
    return (unsigned short)(u >> 16);
}

// Wt[kp] slice (8KB) in MFMA-fragment order: each lane's A-fragment is one
// contiguous 16B chunk. Chunk c (0..511) of slice kp holds, for
// f=c>>6 (=cc*2+m), kg=(c>>5)&1, l31=c&31:
//   e=0..7:  bf16(W[m*32+l31][cc*16+kg*8+e][126-kp])
__global__ void wt_transform(const float* __restrict__ W,
                             unsigned short* __restrict__ Wt) {
    int t  = blockIdx.x * 256 + threadIdx.x;    // 127*512 threads
    int kp = t >> 9, c = t & 511;
    int f = c >> 6, kg = (c >> 5) & 1, l31 = c & 31;
    int cc = f >> 1, m = f & 1;
    int o = m * 32 + l31, ib = cc * 16 + kg * 8;
    const float* src = W + (o * CIN + ib) * KTAPS + (126 - kp);
    unsigned short tmp[8];
    #pragma unroll
    for (int e = 0; e < 8; ++e)
        tmp[e] = f2bf(src[e * KTAPS]);
    uint4 pk;
    pk.x = (unsigned)tmp[0] | ((unsigned)tmp[1] << 16);
    pk.y = (unsigned)tmp[2] | ((unsigned)tmp[3] << 16);
    pk.z = (unsigned)tmp[4] | ((unsigned)tmp[5] << 16);
    pk.w = (unsigned)tmp[6] | ((unsigned)tmp[7] << 16);
    *(uint4*)(Wt + kp * WT_KS + c * 8) = pk;
}

// 16 waves (4/SIMD), per-wave tile 64cout x 64t, taps split 2-way.
// Register diet: acc 64 + A/B ping-pong 32 -> fits the 128-VGPR cap.
__global__ __launch_bounds__(1024, 4)
void conv_mfma(const float* __restrict__ x,
               const unsigned short* __restrict__ Wt,
               float* __restrict__ y) {
    __shared__ __align__(16) char pool[XROWS * XPITCH_B];   // 92160 B
    unsigned short* xs = (unsigned short*)pool;   // [XROWS][72], 144B pitch

    const int tid = threadIdx.x;          // 0..1023
    const int bb  = blockIdx.x >> 5;      // batch
    const int tt  = blockIdx.x & 31;      // t-tile
    const int t0  = tt * TN;

    // ---- stage x window [t0-64, t0+576) transposed into padded rows
    {
        const int cin = tid >> 4;             // 0..63
        const int s   = tid & 15;
        const float* xrow = x + (bb * CIN + cin) * T_LEN;
        for (int j = 0; j < 10; ++j) {
            const int w = 64 * j + 4 * s;
            const int u = t0 - 64 + w;        // global t (16B aligned)
            float4v v;
            if (u >= 0 && u + 4 <= T_LEN) {
                v = *(const float4v*)(xrow + u);
            } else {
                v.x = (u + 0 >= 0 && u + 0 < T_LEN) ? xrow[u + 0] : 0.f;
                v.y = (u + 1 >= 0 && u + 1 < T_LEN) ? xrow[u + 1] : 0.f;
                v.z = (u + 2 >= 0 && u + 2 < T_LEN) ? xrow[u + 2] : 0.f;
                v.w = (u + 3 >= 0 && u + 3 < T_LEN) ? xrow[u + 3] : 0.f;
            }
            #pragma unroll
            for (int e = 0; e < 4; ++e) {
                const int we = w + e;
                const float fv = (e == 0) ? v.x : (e == 1) ? v.y : (e == 2) ? v.z : v.w;
                xs[we * 72 + cin] = f2bf(fv);
            }
        }
    }

    const int lane   = tid & 63;
    const int wv     = tid >> 6;          // 0..15
    const int quad   = wv >> 3;           // tap-half owner (0/1)
    const int ww     = wv & 7;            // t-position (0..7)
    const int l31    = lane & 31;
    const int kg     = lane >> 5;
    const int twbase = ww * 64;           // wave's 64-t range
    const int brow0  = twbase + l31 + 1;  // xs row at k'=0

    const int kp0  = quad ? 64 : 0;
    const int ntap = quad ? 63 : 64;

    // per-lane A-fragment base: + kp*8192 + (cc*2+m)*1024
    const char* ab = (const char*)Wt + lane * 16;

    f32x16 acc[2][2] = {};                // [m][n] -> 64 VGPR
    uint4 aC0, aC1, aN0, aN1;             // A cur/next (m=0,1)
    uint4 bC0, bC1, bN0, bN1;             // B cur/next (n=0,1)

    #define LOADA2(d0, d1, kp, cc)                                          \
        do { const char* p_ = ab + (kp) * 8192 + (cc) * 2048;               \
            d0 = *(const uint4*)(p_);                                       \
            d1 = *(const uint4*)(p_ + 1024); } while (0)

    #define LOADB2(d0, d1, rb, cc)                                          \
        do { const char* xp_ = (const char*)xs + (rb) * XPITCH_B            \
                               + ((2 * (cc) + kg) << 4);                    \
            d0 = *(const uint4*)(xp_);                                      \
            d1 = *(const uint4*)(xp_ + 32 * XPITCH_B); } while (0)

    #define MM4(a0v, a1v, b0v, b1v)                                         \
        do { bf16x8 a0_ = __builtin_bit_cast(bf16x8, a0v);                  \
            bf16x8 a1_ = __builtin_bit_cast(bf16x8, a1v);                   \
            bf16x8 b0_ = __builtin_bit_cast(bf16x8, b0v);                   \
            bf16x8 b1_ = __builtin_bit_cast(bf16x8, b1v);                   \
            acc[0][0] = __builtin_amdgcn_mfma_f32_32x32x16_bf16(a0_, b0_, acc[0][0], 0, 0, 0); \
            acc[0][1] = __builtin_amdgcn_mfma_f32_32x32x16_bf16(a0_, b1_, acc[0][1], 0, 0, 0); \
            acc[1][0] = __builtin_amdgcn_mfma_f32_32x32x16_bf16(a1_, b0_, acc[1][0], 0, 0, 0); \
            acc[1][1] = __builtin_amdgcn_mfma_f32_32x32x16_bf16(a1_, b1_, acc[1][1], 0, 0, 0); \
        } while (0)

    LOADA2(aC0, aC1, kp0, 0);              // prime (overlaps the barrier)
    __syncthreads();                       // xs ready (only barrier pre-merge)
    LOADB2(bC0, bC1, brow0 + kp0, 0);

    // barrier-free main loop; each tap = 4 phases, A/B reg ping-pong.
    // Invariant: (aC,bC) hold phase cc=0 of tap kp on entry and exit.
    for (int kp = kp0; kp < kp0 + ntap; ++kp) {
        const int rb  = brow0 + kp;
        const int kpn = (kp + 1 < KTAPS) ? kp + 1 : KTAPS - 1;  // clamp (dummy)
        LOADA2(aN0, aN1, kp, 1);  LOADB2(bN0, bN1, rb, 1);  MM4(aC0, aC1, bC0, bC1);
        LOADA2(aC0, aC1, kp, 2);  LOADB2(bC0, bC1, rb, 2);  MM4(aN0, aN1, bN0, bN1);
        LOADA2(aN0, aN1, kp, 3);  LOADB2(bN0, bN1, rb, 3);  MM4(aC0, aC1, bC0, bC1);
        LOADA2(aC0, aC1, kpn, 0); LOADB2(bC0, bC1, rb + 1, 0); MM4(aN0, aN1, bN0, bN1);
    }

    // ---- merge quad1 partials into quad0 via LDS (xs dead now)
    __syncthreads();
    float* msm = (float*)pool;            // 64KB: plane (n*16+r) x 512 f32
    #pragma unroll
    for (int m = 0; m < 2; ++m) {
        if (quad == 1) {
            #pragma unroll
            for (int n = 0; n < 2; ++n)
                #pragma unroll
                for (int r = 0; r < 16; ++r)
                    msm[(n * 16 + r) * 512 + ww * 64 + lane] = acc[m][n][r];
        }
        __syncthreads();
        if (quad == 0) {
            #pragma unroll
            for (int n = 0; n < 2; ++n)
                #pragma unroll
                for (int r = 0; r < 16; ++r)
                    acc[m][n][r] += msm[(n * 16 + r) * 512 + ww * 64 + lane];
        }
        __syncthreads();
    }

    // ---- epilogue (quad0): D col = l31 -> t, row = (r&3)+8*(r>>2)+4*kg -> o
    if (quad == 0) {
        const int ybase = (bb * COUT) * T_LEN;
        #pragma unroll
        for (int m = 0; m < 2; ++m) {
            #pragma unroll
            for (int n = 0; n < 2; ++n) {
                const int t = t0 + twbase + n * 32 + l31;
                #pragma unroll
                for (int r = 0; r < 16; ++r) {
                    const int o = m * 32 + (r & 3) + 8 * (r >> 2) + 4 * kg;
                    y[ybase + o * T_LEN + t] = acc[m][n][r];
                }
            }
        }
    }
}

extern "C" void kernel_launch(void* const* d_in, const int* in_sizes, int n_in,
                              void* d_out, int out_size, void* d_ws, size_t ws_size,
                              hipStream_t stream) {
    const float* x = (const float*)d_in[0];
    const float* W = (const float*)d_in[1];
    float* yout = (float*)d_out;
    unsigned short* Wt = (unsigned short*)d_ws;   // 127*4096*2 B ~= 1 MB

    wt_transform<<<(KTAPS * 512) / 256, 256, 0, stream>>>(W, Wt);

    const int grid = 8 * (T_LEN / TN);            // 256 blocks, 1/CU
    conv_mfma<<<grid, 1024, 0, stream>>>(x, Wt, yout);
}

// Round 13
// 116.391 us; speedup vs baseline: 1.1288x; 1.1288x over previous
//
#include <hip/hip_runtime.h>

#define T_LEN 16384
#define CIN   64
#define COUT  64
#define KTAPS 127
#define TN    256          // t-tile per block
#define XROWS 384          // staged x rows
#define XPITCH_B 144       // row pitch in bytes (128 data + 16 pad)
#define WT_KS 4096         // COUT*CIN halfwords per tap slice

typedef __attribute__((ext_vector_type(8)))  __bf16 bf16x8;
typedef __attribute__((ext_vector_type(16))) float  f32x16;
typedef __attribute__((ext_vector_type(4)))  float  float4v;

__device__ inline unsigned short f2bf(float f) {
    unsigned u = __builtin_bit_cast(unsigned, f);
    u += 0x7fffu + ((u >> 16) & 1u);        // round-to-nearest-even
    return (unsigned short)(u >> 16);
}

// Wt[kp] slice (8KB) in MFMA-fragment order (see R5 derivation):
//   chunk c: f=c>>6 (=cc*2+m), kg=(c>>5)&1, l31=c&31
//   e=0..7:  bf16(W[m*32+l31][cc*16+kg*8+e][126-kp])
__global__ void wt_transform(const float* __restrict__ W,
                             unsigned short* __restrict__ Wt) {
    int t  = blockIdx.x * 256 + threadIdx.x;    // 127*512 threads
    int kp = t >> 9, c = t & 511;
    int f = c >> 6, kg = (c >> 5) & 1, l31 = c & 31;
    int cc = f >> 1, m = f & 1;
    int o = m * 32 + l31, ib = cc * 16 + kg * 8;
    const float* src = W + (o * CIN + ib) * KTAPS + (126 - kp);
    unsigned short tmp[8];
    #pragma unroll
    for (int e = 0; e < 8; ++e)
        tmp[e] = f2bf(src[e * KTAPS]);
    uint4 pk;
    pk.x = (unsigned)tmp[0] | ((unsigned)tmp[1] << 16);
    pk.y = (unsigned)tmp[2] | ((unsigned)tmp[3] << 16);
    pk.z = (unsigned)tmp[4] | ((unsigned)tmp[5] << 16);
    pk.w = (unsigned)tmp[6] | ((unsigned)tmp[7] << 16);
    *(uint4*)(Wt + kp * WT_KS + c * 8) = pk;
}

// 256 threads = 4 waves: (quad = tap-half) x (ww = 128-t position).
// 2 blocks/CU (LDS 55.3 KB), independent control flow -> natural anti-phase.
__global__ __launch_bounds__(256, 2)
void conv_mfma(const float* __restrict__ x,
               const unsigned short* __restrict__ Wt,
               float* __restrict__ y) {
    __shared__ __align__(16) char pool[XROWS * XPITCH_B];   // 55296 B
    unsigned short* xs = (unsigned short*)pool;   // [XROWS][72], 144B pitch

    const int tid = threadIdx.x;          // 0..255
    const int bb  = blockIdx.x >> 6;      // batch
    const int tt  = blockIdx.x & 63;      // t-tile
    const int t0  = tt * TN;

    // ---- stage x window [t0-64, t0+320) transposed into padded rows
    {
        const int cin = tid >> 2;             // 0..63
        const int s   = tid & 3;
        const float* xrow = x + (bb * CIN + cin) * T_LEN;
        for (int j = 0; j < 24; ++j) {
            const int w = 16 * j + 4 * s;
            const int u = t0 - 64 + w;        // global t (16B aligned)
            float4v v;
            if (u >= 0 && u + 4 <= T_LEN) {
                v = *(const float4v*)(xrow + u);
            } else {
                v.x = (u + 0 >= 0 && u + 0 < T_LEN) ? xrow[u + 0] : 0.f;
                v.y = (u + 1 >= 0 && u + 1 < T_LEN) ? xrow[u + 1] : 0.f;
                v.z = (u + 2 >= 0 && u + 2 < T_LEN) ? xrow[u + 2] : 0.f;
                v.w = (u + 3 >= 0 && u + 3 < T_LEN) ? xrow[u + 3] : 0.f;
            }
            #pragma unroll
            for (int e = 0; e < 4; ++e) {
                const int we = w + e;
                const float fv = (e == 0) ? v.x : (e == 1) ? v.y : (e == 2) ? v.z : v.w;
                xs[we * 72 + cin] = f2bf(fv);
            }
        }
    }

    const int lane   = tid & 63;
    const int wv     = tid >> 6;          // 0..3
    const int quad   = wv >> 1;           // tap-half owner (0/1)
    const int ww     = wv & 1;            // t-position (0/1)
    const int l31    = lane & 31;
    const int kg     = lane >> 5;
    const int twbase = ww * 128;          // wave's 128-t range
    const int brow0  = twbase + l31 + 1;  // xs row at k'=0

    const int kp0  = quad ? 64 : 0;
    const int ntap = quad ? 63 : 64;

    // per-lane A-fragment global base: + kp*8192 + f*1024, f = cc*2+m
    const char* ab = (const char*)Wt + lane * 16;

    f32x16 acc[2][4] = {};                // [m: o-tile][n: t-tile]
    uint4 a0r[8], a1r[8];                 // ping-pong A prefetch (cross-tap)
    uint4 bA[4], bB[4];                   // B reg double-buffer (cross-cc)

    #define LOADA(dst, kp)                                                  \
        do { const char* p_ = ab + (kp) * 8192;                             \
            _Pragma("unroll")                                               \
            for (int f = 0; f < 8; ++f)                                     \
                dst[f] = *(const uint4*)(p_ + f * 1024); } while (0)

    // one ds_read_b128 per n: lane's B fragment is contiguous 16B
    #define LOADB(dst, rb, cidx)                                            \
        do { const char* xp_ = (const char*)xs + (rb) * XPITCH_B            \
                               + ((2 * (cidx) + kg) << 4);                  \
            _Pragma("unroll")                                               \
            for (int n = 0; n < 4; ++n)                                     \
                dst[n] = *(const uint4*)(xp_ + n * (32 * XPITCH_B));        \
        } while (0)

    #define MFMAB(bv, ar, cidx)                                             \
        do { bf16x8 a0 = __builtin_bit_cast(bf16x8, ar[(cidx) * 2 + 0]);    \
            bf16x8 a1 = __builtin_bit_cast(bf16x8, ar[(cidx) * 2 + 1]);     \
            _Pragma("unroll")                                               \
            for (int n = 0; n < 4; ++n) {                                   \
                bf16x8 b = __builtin_bit_cast(bf16x8, bv[n]);               \
                acc[0][n] = __builtin_amdgcn_mfma_f32_32x32x16_bf16(a0, b, acc[0][n], 0, 0, 0); \
                acc[1][n] = __builtin_amdgcn_mfma_f32_32x32x16_bf16(a1, b, acc[1][n], 0, 0, 0); \
            } } while (0)

    #define TAP(ar, kp)                                                     \
        do {                                                                \
            LOADB(bB, brow0 + (kp), 1);     MFMAB(bA, ar, 0);               \
            LOADB(bA, brow0 + (kp), 2);     MFMAB(bB, ar, 1);               \
            LOADB(bB, brow0 + (kp), 3);     MFMAB(bA, ar, 2);               \
            LOADB(bA, brow0 + (kp) + 1, 0); MFMAB(bB, ar, 3);               \
        } while (0)

    LOADA(a0r, kp0);                       // overlaps the barrier
    __syncthreads();                       // xs ready (only barrier pre-merge)

    // wave stagger within the block (blocks decorrelate on their own)
    for (int z = 0; z < wv; ++z)
        __builtin_amdgcn_s_sleep(2);       // ~128 cyc each

    LOADB(bA, brow0 + kp0, 0);             // prime B pipeline

    // barrier-free main loop: waves drift freely over their tap ranges
    for (int i = 0; i < ntap; i += 2) {
        if (i + 1 < ntap) LOADA(a1r, kp0 + i + 1);    // A issue-early
        TAP(a0r, kp0 + i);
        if (i + 2 < ntap) LOADA(a0r, kp0 + i + 2);
        if (i + 1 < ntap) TAP(a1r, kp0 + i + 1);
    }

    // ---- merge quad1 partials into quad0 via LDS (xs dead now)
    __syncthreads();
    float* msm = (float*)pool;            // 32KB: plane (n*16+r) x 128 f32
    #pragma unroll
    for (int m = 0; m < 2; ++m) {
        if (quad == 1) {
            #pragma unroll
            for (int n = 0; n < 4; ++n)
                #pragma unroll
                for (int r = 0; r < 16; ++r)
                    msm[(n * 16 + r) * 128 + ww * 64 + lane] = acc[m][n][r];
        }
        __syncthreads();
        if (quad == 0) {
            #pragma unroll
            for (int n = 0; n < 4; ++n)
                #pragma unroll
                for (int r = 0; r < 16; ++r)
                    acc[m][n][r] += msm[(n * 16 + r) * 128 + ww * 64 + lane];
        }
        __syncthreads();
    }

    // ---- epilogue (quad0): D col = l31 -> t, row = (r&3)+8*(r>>2)+4*kg -> o
    if (quad == 0) {
        const int ybase = (bb * COUT) * T_LEN;
        #pragma unroll
        for (int m = 0; m < 2; ++m) {
            #pragma unroll
            for (int n = 0; n < 4; ++n) {
                const int t = t0 + twbase + n * 32 + l31;
                #pragma unroll
                for (int r = 0; r < 16; ++r) {
                    const int o = m * 32 + (r & 3) + 8 * (r >> 2) + 4 * kg;
                    y[ybase + o * T_LEN + t] = acc[m][n][r];
                }
            }
        }
    }
}

extern "C" void kernel_launch(void* const* d_in, const int* in_sizes, int n_in,
                              void* d_out, int out_size, void* d_ws, size_t ws_size,
                              hipStream_t stream) {
    const float* x = (const float*)d_in[0];
    const float* W = (const float*)d_in[1];
    float* yout = (float*)d_out;
    unsigned short* Wt = (unsigned short*)d_ws;   // 127*4096*2 B ~= 1 MB

    wt_transform<<<(KTAPS * 512) / 256, 256, 0, stream>>>(W, Wt);

    const int grid = 8 * (T_LEN / TN);            // 512 blocks, 2/CU
    conv_mfma<<<grid, 256, 0, stream>>>(x, Wt, yout);
}

// Round 14
// 113.321 us; speedup vs baseline: 1.1594x; 1.0271x over previous
//
#include <hip/hip_runtime.h>

#define T_LEN 16384
#define CIN   64
#define COUT  64
#define KTAPS 127
#define TN    256          // t-tile per block
#define XROWS 384          // staged x rows
#define XPITCH_B 144       // row pitch in bytes (128 data + 16 pad)
#define WT_KS 4096         // COUT*CIN halfwords per tap slice

typedef __attribute__((ext_vector_type(8)))  __bf16 bf16x8;
typedef __attribute__((ext_vector_type(16))) float  f32x16;
typedef __attribute__((ext_vector_type(4)))  float  float4v;

__device__ inline unsigned short f2bf(float f) {
    unsigned u = __builtin_bit_cast(unsigned, f);
    u += 0x7fffu + ((u >> 16) & 1u);        // round-to-nearest-even
    return (unsigned short)(u >> 16);
}

// Wt[kp] slice (8KB) in MFMA-fragment order (see R5 derivation):
//   chunk c: f=c>>6 (=cc*2+m), kg=(c>>5)&1, l31=c&31
//   e=0..7:  bf16(W[m*32+l31][cc*16+kg*8+e][126-kp])
__global__ void wt_transform(const float* __restrict__ W,
                             unsigned short* __restrict__ Wt) {
    int t  = blockIdx.x * 256 + threadIdx.x;    // 127*512 threads
    int kp = t >> 9, c = t & 511;
    int f = c >> 6, kg = (c >> 5) & 1, l31 = c & 31;
    int cc = f >> 1, m = f & 1;
    int o = m * 32 + l31, ib = cc * 16 + kg * 8;
    const float* src = W + (o * CIN + ib) * KTAPS + (126 - kp);
    unsigned short tmp[8];
    #pragma unroll
    for (int e = 0; e < 8; ++e)
        tmp[e] = f2bf(src[e * KTAPS]);
    uint4 pk;
    pk.x = (unsigned)tmp[0] | ((unsigned)tmp[1] << 16);
    pk.y = (unsigned)tmp[2] | ((unsigned)tmp[3] << 16);
    pk.z = (unsigned)tmp[4] | ((unsigned)tmp[5] << 16);
    pk.w = (unsigned)tmp[6] | ((unsigned)tmp[7] << 16);
    *(uint4*)(Wt + kp * WT_KS + c * 8) = pk;
}

// 256 threads = 4 waves: (quad = tap-half) x (ww = 128-t position).
// 2 blocks/CU; T19 sched_group_barrier gives a time-homogeneous
// [1 ds_read : 2 MFMA] instruction mix so LDS and MFMA pipes run
// concurrently even when co-resident waves phase-lock.
__global__ __launch_bounds__(256, 2)
void conv_mfma(const float* __restrict__ x,
               const unsigned short* __restrict__ Wt,
               float* __restrict__ y) {
    __shared__ __align__(16) char pool[XROWS * XPITCH_B];   // 55296 B
    unsigned short* xs = (unsigned short*)pool;   // [XROWS][72], 144B pitch

    const int tid = threadIdx.x;          // 0..255
    const int bb  = blockIdx.x >> 6;      // batch
    const int tt  = blockIdx.x & 63;      // t-tile
    const int t0  = tt * TN;

    // ---- stage x window [t0-64, t0+320) transposed into padded rows
    {
        const int cin = tid >> 2;             // 0..63
        const int s   = tid & 3;
        const float* xrow = x + (bb * CIN + cin) * T_LEN;
        for (int j = 0; j < 24; ++j) {
            const int w = 16 * j + 4 * s;
            const int u = t0 - 64 + w;        // global t (16B aligned)
            float4v v;
            if (u >= 0 && u + 4 <= T_LEN) {
                v = *(const float4v*)(xrow + u);
            } else {
                v.x = (u + 0 >= 0 && u + 0 < T_LEN) ? xrow[u + 0] : 0.f;
                v.y = (u + 1 >= 0 && u + 1 < T_LEN) ? xrow[u + 1] : 0.f;
                v.z = (u + 2 >= 0 && u + 2 < T_LEN) ? xrow[u + 2] : 0.f;
                v.w = (u + 3 >= 0 && u + 3 < T_LEN) ? xrow[u + 3] : 0.f;
            }
            #pragma unroll
            for (int e = 0; e < 4; ++e) {
                const int we = w + e;
                const float fv = (e == 0) ? v.x : (e == 1) ? v.y : (e == 2) ? v.z : v.w;
                xs[we * 72 + cin] = f2bf(fv);
            }
        }
    }

    const int lane   = tid & 63;
    const int wv     = tid >> 6;          // 0..3
    const int quad   = wv >> 1;           // tap-half owner (0/1)
    const int ww     = wv & 1;            // t-position (0/1)
    const int l31    = lane & 31;
    const int kg     = lane >> 5;
    const int twbase = ww * 128;          // wave's 128-t range
    const int brow0  = twbase + l31 + 1;  // xs row at k'=0

    const int kp0  = quad ? 64 : 0;
    const int ntap = quad ? 63 : 64;

    // per-lane A-fragment global base: + kp*8192 + f*1024, f = cc*2+m
    const char* ab = (const char*)Wt + lane * 16;

    f32x16 acc[2][4] = {};                // [m: o-tile][n: t-tile]
    uint4 a0r[8], a1r[8];                 // ping-pong A prefetch (cross-tap)
    uint4 bA[4], bB[4];                   // B reg double-buffer (cross-cc)

    #define LOADA(dst, kp)                                                  \
        do { const char* p_ = ab + (kp) * 8192;                             \
            _Pragma("unroll")                                               \
            for (int f = 0; f < 8; ++f)                                     \
                dst[f] = *(const uint4*)(p_ + f * 1024); } while (0)

    // one ds_read_b128 per n: lane's B fragment is contiguous 16B
    #define LOADB(dst, rb, cidx)                                            \
        do { const char* xp_ = (const char*)xs + (rb) * XPITCH_B            \
                               + ((2 * (cidx) + kg) << 4);                  \
            _Pragma("unroll")                                               \
            for (int n = 0; n < 4; ++n)                                     \
                dst[n] = *(const uint4*)(xp_ + n * (32 * XPITCH_B));        \
        } while (0)

    #define MFMAB(bv, ar, cidx)                                             \
        do { bf16x8 a0 = __builtin_bit_cast(bf16x8, ar[(cidx) * 2 + 0]);    \
            bf16x8 a1 = __builtin_bit_cast(bf16x8, ar[(cidx) * 2 + 1]);     \
            _Pragma("unroll")                                               \
            for (int n = 0; n < 4; ++n) {                                   \
                bf16x8 b = __builtin_bit_cast(bf16x8, bv[n]);               \
                acc[0][n] = __builtin_amdgcn_mfma_f32_32x32x16_bf16(a0, b, acc[0][n], 0, 0, 0); \
                acc[1][n] = __builtin_amdgcn_mfma_f32_32x32x16_bf16(a1, b, acc[1][n], 0, 0, 0); \
            } } while (0)

    // T19: pin the emitted order to [1 ds_read, 2 MFMA] x 4 per phase.
    // next-phase reads (LOADB nxt) are register-independent of this phase's
    // MFMAs (MFMAB cur), so the weave is legal; compiler inserts counted
    // lgkmcnt waits for the prev-phase regs automatically.
    #define SGB_MIX4()                                                      \
        do { _Pragma("unroll")                                              \
            for (int s_ = 0; s_ < 4; ++s_) {                                \
                __builtin_amdgcn_sched_group_barrier(0x100, 1, 0);          \
                __builtin_amdgcn_sched_group_barrier(0x008, 2, 0);          \
            } } while (0)

    #define PHASE(curv, nxtv, ar, cidx, rbn, cn)                            \
        do { LOADB(nxtv, rbn, cn);                                          \
            MFMAB(curv, ar, cidx);                                          \
            SGB_MIX4(); } while (0)

    #define TAP(ar, kp)                                                     \
        do {                                                                \
            PHASE(bA, bB, ar, 0, brow0 + (kp),     1);                      \
            PHASE(bB, bA, ar, 1, brow0 + (kp),     2);                      \
            PHASE(bA, bB, ar, 2, brow0 + (kp),     3);                      \
            PHASE(bB, bA, ar, 3, brow0 + (kp) + 1, 0);                      \
        } while (0)

    LOADA(a0r, kp0);                       // overlaps the barrier
    __syncthreads();                       // xs ready (only barrier pre-merge)

    // wave stagger within the block (blocks decorrelate on their own)
    for (int z = 0; z < wv; ++z)
        __builtin_amdgcn_s_sleep(2);       // ~128 cyc each

    LOADB(bA, brow0 + kp0, 0);             // prime B pipeline

    // barrier-free main loop: waves drift freely over their tap ranges
    for (int i = 0; i < ntap; i += 2) {
        if (i + 1 < ntap) LOADA(a1r, kp0 + i + 1);    // A issue-early
        TAP(a0r, kp0 + i);
        if (i + 2 < ntap) LOADA(a0r, kp0 + i + 2);
        if (i + 1 < ntap) TAP(a1r, kp0 + i + 1);
    }

    // ---- merge quad1 partials into quad0 via LDS (xs dead now)
    __syncthreads();
    float* msm = (float*)pool;            // 32KB: plane (n*16+r) x 128 f32
    #pragma unroll
    for (int m = 0; m < 2; ++m) {
        if (quad == 1) {
            #pragma unroll
            for (int n = 0; n < 4; ++n)
                #pragma unroll
                for (int r = 0; r < 16; ++r)
                    msm[(n * 16 + r) * 128 + ww * 64 + lane] = acc[m][n][r];
        }
        __syncthreads();
        if (quad == 0) {
            #pragma unroll
            for (int n = 0; n < 4; ++n)
                #pragma unroll
                for (int r = 0; r < 16; ++r)
                    acc[m][n][r] += msm[(n * 16 + r) * 128 + ww * 64 + lane];
        }
        __syncthreads();
    }

    // ---- epilogue (quad0): D col = l31 -> t, row = (r&3)+8*(r>>2)+4*kg -> o
    if (quad == 0) {
        const int ybase = (bb * COUT) * T_LEN;
        #pragma unroll
        for (int m = 0; m < 2; ++m) {
            #pragma unroll
            for (int n = 0; n < 4; ++n) {
                const int t = t0 + twbase + n * 32 + l31;
                #pragma unroll
                for (int r = 0; r < 16; ++r) {
                    const int o = m * 32 + (r & 3) + 8 * (r >> 2) + 4 * kg;
                    y[ybase + o * T_LEN + t] = acc[m][n][r];
                }
            }
        }
    }
}

extern "C" void kernel_launch(void* const* d_in, const int* in_sizes, int n_in,
                              void* d_out, int out_size, void* d_ws, size_t ws_size,
                              hipStream_t stream) {
    const float* x = (const float*)d_in[0];
    const float* W = (const float*)d_in[1];
    float* yout = (float*)d_out;
    unsigned short* Wt = (unsigned short*)d_ws;   // 127*4096*2 B ~= 1 MB

    wt_transform<<<(KTAPS * 512) / 256, 256, 0, stream>>>(W, Wt);

    const int grid = 8 * (T_LEN / TN);            // 512 blocks, 2/CU
    conv_mfma<<<grid, 256, 0, stream>>>(x, Wt, yout);
}